// Round 6
// baseline (472.462 us; speedup 1.0000x reference)
//
#include <hip/hip_runtime.h>
#include <hip/hip_bf16.h>

// LSTM block, fused. Inputs fp32, outputs fp32. bf16 MFMA internally.
// Barrier-free GEMM1: B (gate weights, 0.5MB, L2-resident) is read straight
// from global as contiguous 1KB wave fragments (fragment-linear layout) --
// no LDS staging, no K-loop barriers. LDS = 16KB c_new exchange only.
// 256-thread blocks (4 waves), 64 rows; wave = 64 rows x 128 N'-cols
// (gate-interleaved permutation -> 4-gate elementwise is lane-local).

typedef __attribute__((ext_vector_type(8))) short bf16x8;   // 8 bf16 = 4 VGPRs
typedef __attribute__((ext_vector_type(4))) float f32x4;

static __device__ __forceinline__ unsigned short f2bf(float f) {
    unsigned int u = __builtin_bit_cast(unsigned int, f);
    u += 0x7FFFu + ((u >> 16) & 1u);      // RNE
    return (unsigned short)(u >> 16);
}

static __device__ __forceinline__ bf16x8 cvt8(f32x4 a, f32x4 b) {
    union { bf16x8 v; unsigned short u[8]; } r;
    r.u[0] = f2bf(a[0]); r.u[1] = f2bf(a[1]); r.u[2] = f2bf(a[2]); r.u[3] = f2bf(a[3]);
    r.u[4] = f2bf(b[0]); r.u[5] = f2bf(b[1]); r.u[6] = f2bf(b[2]); r.u[7] = f2bf(b[3]);
    return r.v;
}

static __device__ __forceinline__ float fsig(float x) {
    float e = __builtin_amdgcn_exp2f(-1.44269504f * x);
    return __builtin_amdgcn_rcpf(1.0f + e);
}
static __device__ __forceinline__ float ftanh(float x) {
    float e = __builtin_amdgcn_exp2f(2.8853900818f * x);
    return 1.0f - 2.0f * __builtin_amdgcn_rcpf(e + 1.0f);
}

// ---------------- weight prep: fragment-linear bf16 layouts (r3-proven) ----------------
__global__ void prep_weights(const float* __restrict__ Wf, const float* __restrict__ Wi,
                             const float* __restrict__ Wc, const float* __restrict__ Wo,
                             const float* __restrict__ Wch,
                             unsigned short* __restrict__ WgF,   // 512*256
                             unsigned short* __restrict__ WchF)  // 128*128
{
    int u = blockIdx.x * 256 + threadIdx.x;
    if (u < 16384) {
        int lane = u & 63, nb = (u >> 6) & 31, kc = u >> 11;
        int l15 = lane & 15, lg = lane >> 4;
        int np = nb * 16 + l15;                  // permuted col index
        int wv = np >> 7, g = (np >> 5) & 3, c5 = np & 31;
        int cg = wv * 32 + c5;                   // within-gate col
        int k0 = kc * 32 + lg * 8;
        const float* W = (g == 0) ? Wf : (g == 1) ? Wi : (g == 2) ? Wc : Wo;
        union { bf16x8 v; unsigned short s[8]; } r;
#pragma unroll
        for (int i = 0; i < 8; ++i) r.s[i] = f2bf(W[(size_t)(k0 + i) * 128 + cg]);
        *(bf16x8*)(WgF + (size_t)u * 8) = r.v;
    } else if (u < 16384 + 2048) {
        int u2 = u - 16384;
        int lane = u2 & 63, kt = (u2 >> 6) & 3, nb2 = u2 >> 8;
        int l15 = lane & 15, lg = lane >> 4;
        int n = nb2 * 16 + l15, k0 = kt * 32 + lg * 8;
        union { bf16x8 v; unsigned short s[8]; } r;
#pragma unroll
        for (int i = 0; i < 8; ++i) r.s[i] = f2bf(Wch[(size_t)(k0 + i) * 128 + n]);
        *(bf16x8*)(WchF + (size_t)u2 * 8) = r.v;
    }
}

// ---------------- fused kernel: 64 rows per 256-thread block ----------------
__global__ __launch_bounds__(256, 2) void lstm_fused(
    const float* __restrict__ xg, const float* __restrict__ hg, const float* __restrict__ cg,
    const float* __restrict__ bfv, const float* __restrict__ biv,
    const float* __restrict__ bcv, const float* __restrict__ bov,
    const float* __restrict__ bchv,
    const unsigned short* __restrict__ WgF, const unsigned short* __restrict__ WchF,
    float* __restrict__ out, int nrows)
{
    __shared__ uint4 lds4[1024];                 // 16 KB: c_new exchange
    char* lds = (char*)lds4;

    const int tid  = threadIdx.x;
    const int lane = tid & 63;
    const int wn   = tid >> 6;                   // 0..3 : N' group (128 of 512 cols)
    const int l15  = lane & 15;
    const int lg   = lane >> 4;
    const long m0  = (long)blockIdx.x * 64;

    float* hout = out;
    float* cout = out + (size_t)nrows * 128;

    // biases (lane-local cols: col = wn*32 + hb*16 + l15)
    float bfb[2], bib[2], bcb[2], bob[2], bchb[2];
#pragma unroll
    for (int hb = 0; hb < 2; ++hb) {
        int col = wn * 32 + hb * 16 + l15;
        bfb[hb] = bfv[col]; bib[hb] = biv[col]; bcb[hb] = bcv[col];
        bob[hb] = bov[col]; bchb[hb] = bchv[col];
    }

    f32x4 acc[4][8];
#pragma unroll
    for (int a = 0; a < 4; ++a)
#pragma unroll
        for (int b = 0; b < 8; ++b) acc[a][b] = {0.f, 0.f, 0.f, 0.f};

    // c input loads (independent of GEMM1 -- issue early, land during K-loop)
    float creg[4][2][4];
#pragma unroll
    for (int am = 0; am < 4; ++am)
#pragma unroll
        for (int hb = 0; hb < 2; ++hb)
#pragma unroll
            for (int r = 0; r < 4; ++r) {
                long grow = m0 + am * 16 + lg * 4 + r;
                creg[am][hb][r] = cg[grow * 128 + wn * 32 + hb * 16 + l15];
            }

    // ---- GEMM1: 8 K-chunks of 32, barrier-free, B straight from L2
#pragma unroll 2
    for (int kc = 0; kc < 8; ++kc) {
        // A: 64 rows x 32 cols fp32 -> bf16 frags in-register
        int col = kc * 32 + lg * 8;
        const float* g = (kc < 4) ? (xg + col) : (hg + (col - 128));
        bf16x8 af[4];
#pragma unroll
        for (int am = 0; am < 4; ++am) {
            long row = m0 + am * 16 + l15;
            const f32x4* s = (const f32x4*)(g + row * 128);
            af[am] = cvt8(s[0], s[1]);
        }
        // B: 8 fragment loads (each a contiguous 1KB wave read from L2) + MFMA
        const char* bb = (const char*)WgF + (size_t)kc * 32768 + wn * 8192;
#pragma unroll
        for (int bn = 0; bn < 8; ++bn) {
            bf16x8 bfr = *(const bf16x8*)(bb + bn * 1024 + lane * 16);
#pragma unroll
            for (int am = 0; am < 4; ++am)
                acc[am][bn] = __builtin_amdgcn_mfma_f32_16x16x32_bf16(af[am], bfr, acc[am][bn], 0, 0, 0);
        }
    }

    // ---- elementwise: gates -> c_new (fp32 regs + bf16 exchange into LDS)
    float cn[4][2][4];
#pragma unroll
    for (int am = 0; am < 4; ++am)
#pragma unroll
        for (int hb = 0; hb < 2; ++hb)
#pragma unroll
            for (int r = 0; r < 4; ++r) {
                float f  = fsig(acc[am][0 + hb][r] + bfb[hb]);
                float i  = fsig(acc[am][2 + hb][r] + bib[hb]);
                float ct = ftanh(acc[am][4 + hb][r] + bcb[hb]);
                float cv = f * creg[am][hb][r] + i * ct;
                cn[am][hb][r] = cv;
                int blk  = am * 4 + wn;                       // (row-blk, kt=wn)
                int slot = (hb * 2 + (l15 >> 3)) * 16 + (lg * 4 + r);
                *(unsigned short*)(lds + blk * 1024 + slot * 16 + (l15 & 7) * 2) = f2bf(cv);
            }
    __syncthreads();                             // the only barrier

    // ---- GEMM2: t2[64,128] = c_new @ Wch ; Wch frags straight from L2
    f32x4 acc2[4][2];
#pragma unroll
    for (int a = 0; a < 4; ++a) { acc2[a][0] = {0.f,0.f,0.f,0.f}; acc2[a][1] = {0.f,0.f,0.f,0.f}; }
#pragma unroll
    for (int kt = 0; kt < 4; ++kt) {
        bf16x8 a2[4];
#pragma unroll
        for (int m = 0; m < 4; ++m)
            a2[m] = *(const bf16x8*)(lds + (m * 4 + kt) * 1024 + lane * 16);
#pragma unroll
        for (int n2 = 0; n2 < 2; ++n2) {
            bf16x8 b2 = *(const bf16x8*)((const char*)WchF + ((wn * 2 + n2) * 4 + kt) * 1024 + lane * 16);
#pragma unroll
            for (int m = 0; m < 4; ++m)
                acc2[m][n2] = __builtin_amdgcn_mfma_f32_16x16x32_bf16(a2[m], b2, acc2[m][n2], 0, 0, 0);
        }
    }

    // ---- h = o * tanh(t2 + bch); store h and c_new (fp32)
#pragma unroll
    for (int am = 0; am < 4; ++am)
#pragma unroll
        for (int hb = 0; hb < 2; ++hb)
#pragma unroll
            for (int r = 0; r < 4; ++r) {
                long grow = m0 + am * 16 + lg * 4 + r;
                int col = wn * 32 + hb * 16 + l15;
                float o  = fsig(acc[am][6 + hb][r] + bob[hb]);
                float hv = o * ftanh(acc2[am][hb][r] + bchb[hb]);
                hout[grow * 128 + col] = hv;
                cout[grow * 128 + col] = cn[am][hb][r];
            }
}

extern "C" void kernel_launch(void* const* d_in, const int* in_sizes, int n_in,
                              void* d_out, int out_size, void* d_ws, size_t ws_size,
                              hipStream_t stream)
{
    const float* x   = (const float*)d_in[0];
    const float* h   = (const float*)d_in[1];
    const float* c   = (const float*)d_in[2];
    const float* Wf  = (const float*)d_in[3];
    const float* bf_ = (const float*)d_in[4];
    const float* Wi  = (const float*)d_in[5];
    const float* bi_ = (const float*)d_in[6];
    const float* Wc  = (const float*)d_in[7];
    const float* bc_ = (const float*)d_in[8];
    const float* Wo  = (const float*)d_in[9];
    const float* bo_ = (const float*)d_in[10];
    const float* Wch = (const float*)d_in[11];
    const float* bch = (const float*)d_in[12];

    unsigned short* WgF  = (unsigned short*)d_ws;         // 512*256 bf16 fragment-linear
    unsigned short* WchF = WgF + 512 * 256;               // 128*128 bf16 fragment-linear
    float* out = (float*)d_out;

    int nrows = in_sizes[0] / 128;                        // 262144

    prep_weights<<<dim3(72), dim3(256), 0, stream>>>(Wf, Wi, Wc, Wo, Wch, WgF, WchF);
    lstm_fused<<<dim3(nrows / 64), dim3(256), 0, stream>>>(
        x, h, c, bf_, bi_, bc_, bo_, bch, WgF, WchF, out, nrows);
}

// Round 7
// 147.592 us; speedup vs baseline: 3.2011x; 3.2011x over previous
//
#include <hip/hip_runtime.h>
#include <hip/hip_bf16.h>

// LSTM block, fused. Inputs fp32, outputs fp32. bf16 MFMA internally.
// KEY IDEA: all weights live in REGISTERS (Wg 256KB bf16 = 128 VGPR/wave across
// 8 waves x 64 gate-interleaved cols; Wch = 16 VGPR). GEMM1 has zero B-memory
// traffic. One block of 512 threads per CU (grid=256), 32-row tiles, ONE
// barrier per tile (lgkmcnt-only: global prefetch stays in flight).
// A: global->reg->bf16->LDS frags (XOR-swizzled, conflict-free), double-buffered.

typedef __attribute__((ext_vector_type(8))) short bf16x8;   // 8 bf16 = 4 VGPRs
typedef __attribute__((ext_vector_type(4))) float f32x4;

static __device__ __forceinline__ unsigned short f2bf(float f) {
    unsigned int u = __builtin_bit_cast(unsigned int, f);
    u += 0x7FFFu + ((u >> 16) & 1u);      // RNE
    return (unsigned short)(u >> 16);
}

static __device__ __forceinline__ bf16x8 cvt8(f32x4 a, f32x4 b) {
    union { bf16x8 v; unsigned short u[8]; } r;
    r.u[0] = f2bf(a[0]); r.u[1] = f2bf(a[1]); r.u[2] = f2bf(a[2]); r.u[3] = f2bf(a[3]);
    r.u[4] = f2bf(b[0]); r.u[5] = f2bf(b[1]); r.u[6] = f2bf(b[2]); r.u[7] = f2bf(b[3]);
    return r.v;
}

static __device__ __forceinline__ float fsig(float x) {
    float e = __builtin_amdgcn_exp2f(-1.44269504f * x);
    return __builtin_amdgcn_rcpf(1.0f + e);
}
static __device__ __forceinline__ float ftanh(float x) {
    float e = __builtin_amdgcn_exp2f(2.8853900818f * x);
    return 1.0f - 2.0f * __builtin_amdgcn_rcpf(e + 1.0f);
}

// ---------------- weight prep: fragment-linear bf16, 16-col gate interleave ----
// WgF: 256 frags of 1KB, frag index = ks*32 + wn*4 + g  (ks 0..7, wn 0..7, g 0..3)
//   lane l: within-gate col = wn*16 + (l&15), k = ks*32 + (l>>4)*8 .. +8
// WchF: 32 frags, index = kt*8 + wn: col = wn*16 + (l&15), k = kt*32 + (l>>4)*8
__global__ void prep_weights(const float* __restrict__ Wf, const float* __restrict__ Wi,
                             const float* __restrict__ Wc, const float* __restrict__ Wo,
                             const float* __restrict__ Wch,
                             unsigned short* __restrict__ WgF,   // 512*256
                             unsigned short* __restrict__ WchF)  // 128*128
{
    int u = blockIdx.x * 256 + threadIdx.x;
    if (u < 16384) {
        int lane = u & 63, g = (u >> 6) & 3, wn = (u >> 8) & 7, ks = u >> 11;
        int l15 = lane & 15, lg = lane >> 4;
        int cg = wn * 16 + l15;
        int k0 = ks * 32 + lg * 8;
        const float* W = (g == 0) ? Wf : (g == 1) ? Wi : (g == 2) ? Wc : Wo;
        union { bf16x8 v; unsigned short s[8]; } r;
#pragma unroll
        for (int i = 0; i < 8; ++i) r.s[i] = f2bf(W[(size_t)(k0 + i) * 128 + cg]);
        *(bf16x8*)(WgF + (size_t)u * 8) = r.v;
    } else if (u < 16384 + 2048) {
        int u2 = u - 16384;
        int lane = u2 & 63, wn = (u2 >> 6) & 7, kt = u2 >> 9;
        int l15 = lane & 15, lg = lane >> 4;
        int col = wn * 16 + l15, k0 = kt * 32 + lg * 8;
        union { bf16x8 v; unsigned short s[8]; } r;
#pragma unroll
        for (int i = 0; i < 8; ++i) r.s[i] = f2bf(Wch[(size_t)(k0 + i) * 128 + col]);
        *(bf16x8*)(WchF + (size_t)u2 * 8) = r.v;
    }
}

// ---------------- fused kernel: 1024 rows per 512-thread block, 32-row tiles ----
// LDS (48 KB): A frags dbuf [0,16K)+[16K,32K); c_ex dbuf [32K,40K)+[40K,48K)
__global__ __launch_bounds__(512, 2) void lstm_fused(
    const float* __restrict__ xg, const float* __restrict__ hg, const float* __restrict__ cg,
    const float* __restrict__ bfv, const float* __restrict__ biv,
    const float* __restrict__ bcv, const float* __restrict__ bov,
    const float* __restrict__ bchv,
    const unsigned short* __restrict__ WgF, const unsigned short* __restrict__ WchF,
    float* __restrict__ out, int nrows)
{
    __shared__ uint4 lds4[3072];                 // 48 KB
    char* lds = (char*)lds4;

    const int tid  = threadIdx.x;
    const int lane = tid & 63;
    const int wn   = tid >> 6;                   // 0..7: owns cols wn*16..+16 of each gate
    const int l15  = lane & 15;
    const int lg   = lane >> 4;
    const long base = (long)blockIdx.x << 10;    // 1024 rows per block

    float* hout = out;
    float* cout = out + (size_t)nrows * 128;

    const int colc = wn * 16 + l15;              // lane-local output column
    const float bfb = bfv[colc], bib = biv[colc], bcb = bcv[colc],
                bob = bov[colc], bchb = bchv[colc];

    // ---- weights into registers (L2-resident source; read once per block)
    bf16x8 Breg[8][4];                           // [ks][gate] : 128 VGPRs
#pragma unroll
    for (int ks = 0; ks < 8; ++ks)
#pragma unroll
        for (int g = 0; g < 4; ++g)
            Breg[ks][g] = *(const bf16x8*)(WgF + (size_t)((ks * 32 + wn * 4 + g) * 512 + lane * 8));
    bf16x8 Wreg[4];                              // [kt] : 16 VGPRs
#pragma unroll
    for (int kt = 0; kt < 4; ++kt)
        Wreg[kt] = *(const bf16x8*)(WchF + (size_t)((kt * 8 + wn) * 512 + lane * 8));

    // ---- A-staging thread coords (thread u stages 16 k-elems of one row)
    const int rowA = tid >> 4;                   // 0..31
    const int kgA  = tid & 15;                   // 16-elem k-group
    const int ksA  = kgA >> 1;
    const int lgA  = (kgA & 1) * 2;
    const int amA  = rowA >> 4;
    const int l15A = rowA & 15;
    const int aoff0 = (amA * 8 + ksA) * 1024 + ((((lgA    ) * 16 + l15A) * 16) ^ (ksA << 4));
    const int aoff1 = (amA * 8 + ksA) * 1024 + ((((lgA + 1) * 16 + l15A) * 16) ^ (ksA << 4));
    const float* asrc = (kgA < 8) ? (xg + kgA * 16) : (hg + (kgA - 8) * 16);

    // ---- prologue: stage A(0) into buf0; load c(0)
    {
        const float* s = asrc + (base + rowA) * 128;
        f32x4 v0 = ((const f32x4*)s)[0], v1 = ((const f32x4*)s)[1],
              v2 = ((const f32x4*)s)[2], v3 = ((const f32x4*)s)[3];
        *(bf16x8*)(lds + aoff0) = cvt8(v0, v1);
        *(bf16x8*)(lds + aoff1) = cvt8(v2, v3);
    }
    float creg[8];
#pragma unroll
    for (int am = 0; am < 2; ++am)
#pragma unroll
        for (int r = 0; r < 4; ++r)
            creg[am * 4 + r] = cg[(base + am * 16 + lg * 4 + r) * 128 + colc];
    __syncthreads();

    f32x4 acc[2][4];                             // [am][gate]
#pragma unroll
    for (int am = 0; am < 2; ++am)
#pragma unroll
        for (int g = 0; g < 4; ++g) acc[am][g] = {0.f, 0.f, 0.f, 0.f};

    for (int t = 0; t < 32; ++t) {
        const int cur = t & 1;
        const long m0 = base + t * 32;

        // step1: issue A-raw loads for tile t+1 (consumed at step5)
        f32x4 a0, a1, a2, a3;
        if (t < 31) {
            const float* s = asrc + (m0 + 32 + rowA) * 128;
            a0 = ((const f32x4*)s)[0]; a1 = ((const f32x4*)s)[1];
            a2 = ((const f32x4*)s)[2]; a3 = ((const f32x4*)s)[3];
        }
        // step2: issue c loads for tile t+1 (consumed next iteration)
        float cregN[8];
        if (t < 31) {
#pragma unroll
            for (int am = 0; am < 2; ++am)
#pragma unroll
                for (int r = 0; r < 4; ++r)
                    cregN[am * 4 + r] = cg[(m0 + 32 + am * 16 + lg * 4 + r) * 128 + colc];
        }
        // step3: gates MFMA — A from LDS, B from registers (no memory for B)
        const char* ab = lds + cur * 16384;
#pragma unroll
        for (int ks = 0; ks < 8; ++ks) {
            bf16x8 af0 = *(const bf16x8*)(ab + (ks       ) * 1024 + ((lane * 16) ^ (ks << 4)));
            bf16x8 af1 = *(const bf16x8*)(ab + (8 + ks   ) * 1024 + ((lane * 16) ^ (ks << 4)));
#pragma unroll
            for (int g = 0; g < 4; ++g) {
                acc[0][g] = __builtin_amdgcn_mfma_f32_16x16x32_bf16(af0, Breg[ks][g], acc[0][g], 0, 0, 0);
                acc[1][g] = __builtin_amdgcn_mfma_f32_16x16x32_bf16(af1, Breg[ks][g], acc[1][g], 0, 0, 0);
            }
        }
        // step4: elementwise -> c_new; store c now; write c_ex (bf16 A-frags for GEMM2)
        char* cex = lds + 32768 + cur * 8192;
        const int cslotbase = ((wn & 1) * 2 + (l15 >> 3)) * 16;
#pragma unroll
        for (int am = 0; am < 2; ++am)
#pragma unroll
            for (int r = 0; r < 4; ++r) {
                float f  = fsig(acc[am][0][r] + bfb);
                float i  = fsig(acc[am][1][r] + bib);
                float ct = ftanh(acc[am][2][r] + bcb);
                float cv = f * creg[am * 4 + r] + i * ct;
                cout[(m0 + am * 16 + lg * 4 + r) * 128 + colc] = cv;
                *(unsigned short*)(cex + (am * 4 + (wn >> 1)) * 1024
                                       + (cslotbase + lg * 4 + r) * 16 + (l15 & 7) * 2) = f2bf(cv);
            }
        // step5: cvt A(t+1) -> LDS buf cur^1
        if (t < 31) {
            char* fb = lds + (cur ^ 1) * 16384;
            *(bf16x8*)(fb + aoff0) = cvt8(a0, a1);
            *(bf16x8*)(fb + aoff1) = cvt8(a2, a3);
        }
        // step6: ONE barrier per tile; lgkm-only (global prefetch stays in flight)
        asm volatile("s_waitcnt lgkmcnt(0)" ::: "memory");
        __builtin_amdgcn_s_barrier();
        __builtin_amdgcn_sched_barrier(0);
        // step7: GEMM2 (c_ex x Wch-regs) + h epilogue
        f32x4 acc2_0 = {0.f, 0.f, 0.f, 0.f}, acc2_1 = {0.f, 0.f, 0.f, 0.f};
#pragma unroll
        for (int kt = 0; kt < 4; ++kt) {
            bf16x8 p0 = *(const bf16x8*)(cex + (kt    ) * 1024 + lane * 16);
            bf16x8 p1 = *(const bf16x8*)(cex + (4 + kt) * 1024 + lane * 16);
            acc2_0 = __builtin_amdgcn_mfma_f32_16x16x32_bf16(p0, Wreg[kt], acc2_0, 0, 0, 0);
            acc2_1 = __builtin_amdgcn_mfma_f32_16x16x32_bf16(p1, Wreg[kt], acc2_1, 0, 0, 0);
        }
#pragma unroll
        for (int r = 0; r < 4; ++r) {
            float o0 = fsig(acc[0][3][r] + bob);
            hout[(m0 +      lg * 4 + r) * 128 + colc] = o0 * ftanh(acc2_0[r] + bchb);
            float o1 = fsig(acc[1][3][r] + bob);
            hout[(m0 + 16 + lg * 4 + r) * 128 + colc] = o1 * ftanh(acc2_1[r] + bchb);
        }
        // roll state
#pragma unroll
        for (int am = 0; am < 2; ++am)
#pragma unroll
            for (int g = 0; g < 4; ++g) acc[am][g] = {0.f, 0.f, 0.f, 0.f};
        if (t < 31) {
#pragma unroll
            for (int q = 0; q < 8; ++q) creg[q] = cregN[q];
        }
    }
}

extern "C" void kernel_launch(void* const* d_in, const int* in_sizes, int n_in,
                              void* d_out, int out_size, void* d_ws, size_t ws_size,
                              hipStream_t stream)
{
    const float* x   = (const float*)d_in[0];
    const float* h   = (const float*)d_in[1];
    const float* c   = (const float*)d_in[2];
    const float* Wf  = (const float*)d_in[3];
    const float* bf_ = (const float*)d_in[4];
    const float* Wi  = (const float*)d_in[5];
    const float* bi_ = (const float*)d_in[6];
    const float* Wc  = (const float*)d_in[7];
    const float* bc_ = (const float*)d_in[8];
    const float* Wo  = (const float*)d_in[9];
    const float* bo_ = (const float*)d_in[10];
    const float* Wch = (const float*)d_in[11];
    const float* bch = (const float*)d_in[12];

    unsigned short* WgF  = (unsigned short*)d_ws;         // 512*256 bf16 fragment-linear
    unsigned short* WchF = WgF + 512 * 256;               // 128*128 bf16 fragment-linear
    float* out = (float*)d_out;

    int nrows = in_sizes[0] / 128;                        // 262144

    prep_weights<<<dim3(72), dim3(256), 0, stream>>>(Wf, Wi, Wc, Wo, Wch, WgF, WchF);
    lstm_fused<<<dim3(nrows / 1024), dim3(512), 0, stream>>>(
        x, h, c, bf_, bi_, bc_, bo_, bch, WgF, WchF, out, nrows);
}